// Round 7
// baseline (231.713 us; speedup 1.0000x reference)
//
#include <hip/hip_runtime.h>
#include <cstddef>

#define NB 64
#define NA 5
#define NC 20
#define NH 64
#define NW 64
#define MAXB 50
#define HWSZ (NH * NW)
#define CELLS 5
#define CELLS_PER_BLK (256 * CELLS)    // 1280
#define NABLK 64                       // A-blocks (bid 0..63)
#define NBBLK 1024                     // B-blocks: 1024*1280 = 1,310,720 cells; 16 blk/batch
#define NPART (NABLK + NBBLK)          // 1088

__constant__ float c_aw[NA] = {1.3221f, 3.19275f, 5.05587f, 9.47112f, 11.2364f};
__constant__ float c_ah[NA] = {1.73145f, 4.00944f, 8.09892f, 4.84053f, 10.0071f};

__device__ __forceinline__ float sigmoidf_(float v) {
    return 1.f / (1.f + __expf(-v));
}

__global__ __launch_bounds__(256, 4) void region_loss_main(const float* __restrict__ out,
                                                           const float* __restrict__ tgt,
                                                           float* __restrict__ partials) {
    const int bid = blockIdx.x;
    const int t = threadIdx.x;

    __shared__ __align__(16) float sbox[MAXB][8];  // xlo,xhi,ylo,yhi,0.375*area
    __shared__ float s_cls[MAXB], s_gx[MAXB], s_gy[MAXB], s_gw[MAXB], s_gh[MAXB];
    __shared__ int s_flat[MAXB], s_bestn[MAXB];
    __shared__ int s_nv;
    __shared__ float sred[4];

    if (bid < NABLK) {
        // ---------------- A: assigned-cell terms (wave 0 does the work) -------
        const int b = bid;
        if (t < 64) {
            float xv = (t < MAXB) ? tgt[(size_t)b * (MAXB * 5) + t * 5 + 1] : 0.f;
            unsigned long long mk = __ballot(xv != 0.f);
            if (t == 0) {
                unsigned long long inv = (~mk) & ((1ull << MAXB) - 1ull);
                s_nv = inv ? (__ffsll(inv) - 1) : MAXB;
            }
        }
        if (t < MAXB) {
            const float* tp = tgt + (size_t)b * (MAXB * 5) + t * 5;
            s_cls[t] = tp[0];
            s_gx[t] = tp[1] * NW; s_gy[t] = tp[2] * NH;
            s_gw[t] = tp[3] * NW; s_gh[t] = tp[4] * NH;
        }
        __syncthreads();
        const int nv = s_nv;

        if (t < MAXB) {
            if (t < nv) {
                float gw = s_gw[t], gh = s_gh[t];
                float best = -1.f; int bn = 0;
                for (int a = 0; a < NA; ++a) {
                    float ca = fminf(c_aw[a], gw) * fminf(c_ah[a], gh);
                    float ua = c_aw[a] * c_ah[a] + gw * gh - ca;
                    float iou = ca / ua;
                    if (iou > best) { best = iou; bn = a; }   // first max wins
                }
                int gi = (int)s_gx[t], gj = (int)s_gy[t];
                s_bestn[t] = bn;
                s_flat[t] = (bn * NH + gj) * NW + gi;
            } else {
                s_flat[t] = -1 - t;
            }
        }
        __syncthreads();

        float loss = 0.f;
        if (t < nv) {
            // last-writer-wins dedupe (matches serial scatter order)
            bool winner = true;
            const int myf = s_flat[t];
            for (int t2 = t + 1; t2 < nv; ++t2) winner = winner && (s_flat[t2] != myf);
            if (winner) {
                const int a = s_bestn[t];
                const int gi = myf & (NW - 1);
                const int gj = (myf >> 6) & (NH - 1);
                const size_t base = (((size_t)b * NA + a) * 25) * HWSZ + gj * NW + gi;
                float x = sigmoidf_(out[base]);
                float y = sigmoidf_(out[base + HWSZ]);
                float w = __expf(out[base + 2 * HWSZ]);
                float h = __expf(out[base + 3 * HWSZ]);
                float conf = sigmoidf_(out[base + 4 * HWSZ]);

                float gx = s_gx[t], gy = s_gy[t], gw = s_gw[t], gh = s_gh[t];
                float tx = gx - (float)gi, ty = gy - (float)gj;
                float tw = gw / c_aw[a], th = gh / c_ah[a];
                float dx = x - tx, dy = y - ty, dw = w - tw, dh = h - th;
                loss += 0.5f * (dx * dx + dy * dy + dw * dw + dh * dh);

                float px = x + (float)gi, py = y + (float)gj;
                float pw = w * c_aw[a], ph = h * c_ah[a];
                float pxlo = px - 0.5f * pw, pxhi = px + 0.5f * pw;
                float pylo = py - 0.5f * ph, pyhi = py + 0.5f * ph;
                float parea = pw * ph;

                {   // assigned conf term minus what B added for this cell
                    float cw  = fminf(pxhi, gx + 0.5f * gw) - fmaxf(pxlo, gx - 0.5f * gw);
                    float chh = fminf(pyhi, gy + 0.5f * gh) - fmaxf(pylo, gy - 0.5f * gh);
                    float ca  = fmaxf(cw, 0.f) * fmaxf(chh, 0.f);
                    float ua  = parea + gw * gh - ca;
                    float tconf = ca / ua;
                    float mm = -1e30f;
                    for (int t2 = 0; t2 < nv; ++t2) {
                        float gw2 = s_gw[t2], gh2 = s_gh[t2];
                        float cw2 = fminf(pxhi, s_gx[t2] + 0.5f * gw2) -
                                    fmaxf(pxlo, s_gx[t2] - 0.5f * gw2);
                        float ch2 = fminf(pyhi, s_gy[t2] + 0.5f * gh2) -
                                    fmaxf(pylo, s_gy[t2] - 0.5f * gh2);
                        float ca2 = fmaxf(cw2, 0.f) * fmaxf(ch2, 0.f);
                        mm = fmaxf(mm, ca2 - 0.375f * gw2 * gh2);
                    }
                    bool sil = mm > 0.375f * parea;
                    float base_c = sil ? 0.f : 0.5f * conf * conf;
                    float dc = conf - tconf;
                    loss += 0.5f * dc * dc - base_c;
                }

                {   // class cross-entropy
                    const int lab = (int)s_cls[t];
                    float mmax = -1e30f, llab = 0.f;
                    for (int c = 0; c < NC; ++c) {
                        float l = out[base + (size_t)(5 + c) * HWSZ];
                        mmax = fmaxf(mmax, l);
                        if (c == lab) llab = l;
                    }
                    float se = 0.f;
                    for (int c = 0; c < NC; ++c)
                        se += __expf(out[base + (size_t)(5 + c) * HWSZ] - mmax);
                    loss += -(llab - mmax - logf(se));
                }
            }
        }
        if (t < 64) {
            for (int off = 32; off; off >>= 1) loss += __shfl_down(loss, off, 64);
            if (t == 0) partials[bid] = loss;
        }
        return;
    }

    // ---------------- B: default no-obj conf loss over a flat cell range ------
    const int g = bid - NABLK;          // 0..1023
    const int b = g >> 4;               // 16 blocks per batch (16*1280 = 5*4096)
    const int cell0 = g * CELLS_PER_BLK;

    // wave 0: validity ballot + masked box staging (single wave, no extra sync)
    if (t < 64) {
        float xv = (t < MAXB) ? tgt[(size_t)b * (MAXB * 5) + t * 5 + 1] : 0.f;
        unsigned long long mk = __ballot(xv != 0.f);
        unsigned long long inv = (~mk) & ((1ull << MAXB) - 1ull);
        int nv = inv ? (__ffsll(inv) - 1) : MAXB;
        if (t < MAXB) {
            bool val = t < nv;
            const float* tp = tgt + (size_t)b * (MAXB * 5) + t * 5;
            float gx = tp[1] * (float)NW, gy = tp[2] * (float)NH;
            float gw = tp[3] * (float)NW, gh = tp[4] * (float)NH;
            sbox[t][0] = val ? gx - 0.5f * gw : 0.f;
            sbox[t][1] = val ? gx + 0.5f * gw : 0.f;
            sbox[t][2] = val ? gy - 0.5f * gh : 0.f;
            sbox[t][3] = val ? gy + 0.5f * gh : 0.f;
            sbox[t][4] = val ? 0.375f * gw * gh : 1e30f;  // masked: never silences
        }
    }

    float pxlo[CELLS], pxhi[CELLS], pylo[CELLS], pyhi[CELLS];
    float m[CELLS], rhs[CELLS], hc[CELLS];
    const float fi = (float)(t & 63);
#pragma unroll
    for (int cc = 0; cc < CELLS; ++cc) {
        const int cell = cell0 + cc * 256;     // block-uniform
        const int ba = cell >> 12;             // = b*5 + a (uniform per cc)
        const int a = ba - b * NA;
        const int hw = (cell & 4095) + t;
        const float fj = (float)(hw >> 6);
        const float aw = c_aw[a], ah = c_ah[a];
        const float* p = out + (size_t)ba * (25 * HWSZ) + hw;
        float px = sigmoidf_(p[0]) + fi;
        float py = sigmoidf_(p[HWSZ]) + fj;
        float pw = __expf(p[2 * HWSZ]) * aw;
        float ph = __expf(p[3 * HWSZ]) * ah;
        float cf = sigmoidf_(p[4 * HWSZ]);
        pxlo[cc] = px - 0.5f * pw; pxhi[cc] = px + 0.5f * pw;
        pylo[cc] = py - 0.5f * ph; pyhi[cc] = py + 0.5f * ph;
        rhs[cc] = 0.375f * pw * ph;
        hc[cc]  = 0.5f * cf * cf;
        m[cc]   = -1e30f;
    }
    __syncthreads();

    // fixed trip count -> unrolled, LDS reads pipelined
#pragma unroll 10
    for (int t2 = 0; t2 < MAXB; ++t2) {
        const float4 bb = *reinterpret_cast<const float4*>(&sbox[t2][0]);
        const float s2 = sbox[t2][4];
#pragma unroll
        for (int cc = 0; cc < CELLS; ++cc) {
            float cw = fminf(pxhi[cc], bb.y) - fmaxf(pxlo[cc], bb.x);
            float ch = fminf(pyhi[cc], bb.w) - fmaxf(pylo[cc], bb.z);
            float ca_m = fmaf(fmaxf(cw, 0.f), fmaxf(ch, 0.f), -s2);
            m[cc] = fmaxf(m[cc], ca_m);       // sil <=> max > 0.375*parea
        }
    }

    float v = 0.f;
#pragma unroll
    for (int cc = 0; cc < CELLS; ++cc) v += (m[cc] > rhs[cc]) ? 0.f : hc[cc];

    for (int off = 32; off; off >>= 1) v += __shfl_down(v, off, 64);
    if ((t & 63) == 0) sred[t >> 6] = v;
    __syncthreads();
    if (t == 0) partials[bid] = sred[0] + sred[1] + sred[2] + sred[3];
}

// ---------------- deterministic final reduce (2nd graph node) ----------------
__global__ __launch_bounds__(256) void reduce_kernel(const float* __restrict__ partials,
                                                     float* __restrict__ outp) {
    float v = 0.f;
    for (int idx = threadIdx.x; idx < NPART; idx += 256) v += partials[idx];
    for (int off = 32; off; off >>= 1) v += __shfl_down(v, off, 64);
    __shared__ float s[4];
    if ((threadIdx.x & 63) == 0) s[threadIdx.x >> 6] = v;
    __syncthreads();
    if (threadIdx.x == 0) outp[0] = s[0] + s[1] + s[2] + s[3];
}

extern "C" void kernel_launch(void* const* d_in, const int* in_sizes, int n_in,
                              void* d_out, int out_size, void* d_ws, size_t ws_size,
                              hipStream_t stream) {
    const float* out_t = (const float*)d_in[0];
    const float* tgt   = (const float*)d_in[1];
    float* loss = (float*)d_out;
    float* partials = (float*)d_ws;   // NPART floats, fully rewritten each call

    // MEASUREMENT ROUND: launch the (unchanged) main kernel 9x back-to-back.
    // Idempotent: every launch writes the same values to partials (plain
    // deterministic stores), so correctness is unaffected; the dur_us slope
    // vs R6 gives T_main = (dur_R7 - dur_R6) / 8 without needing rocprof rows.
    for (int r = 0; r < 9; ++r)
        region_loss_main<<<NPART, 256, 0, stream>>>(out_t, tgt, partials);
    reduce_kernel<<<1, 256, 0, stream>>>(partials, loss);
}

// Round 8
// 25.939 us; speedup vs baseline: 8.9330x; 8.9330x over previous
//
#include <hip/hip_runtime.h>
#include <cstddef>

#define NB 64
#define NA 5
#define NC 20
#define NH 64
#define NW 64
#define MAXB 50
#define HWSZ (NH * NW)
#define CELLS 5
#define CELLS_PER_BLK (256 * CELLS)    // 1280
#define NABLK 64                       // A-blocks (bid 0..63)
#define NBBLK 1024                     // B-blocks: 1024*1280 = 1,310,720 cells
#define NPART (NABLK + NBBLK)          // 1088

__constant__ float c_aw[NA] = {1.3221f, 3.19275f, 5.05587f, 9.47112f, 11.2364f};
__constant__ float c_ah[NA] = {1.73145f, 4.00944f, 8.09892f, 4.84053f, 10.0071f};

__device__ __forceinline__ float sigmoidf_(float v) {
    return 1.f / (1.f + __expf(-v));
}

__global__ __launch_bounds__(256, 4) void region_loss_main(const float* __restrict__ out,
                                                           const float* __restrict__ tgt,
                                                           float* __restrict__ partials) {
    const int bid = blockIdx.x;
    const int t = threadIdx.x;

    __shared__ __align__(16) float sbox[MAXB][8];  // xlo,xhi,ylo,yhi,0.375*area,gy,gh,-
    __shared__ float s_cls[MAXB], s_gx[MAXB], s_gy[MAXB], s_gw[MAXB], s_gh[MAXB];
    __shared__ int s_flat[MAXB], s_bestn[MAXB];
    __shared__ int s_nv;
    __shared__ float sred[4];

    if (bid < NABLK) {
        // ---------------- A: assigned-cell terms (wave 0 does the work) -------
        const int b = bid;
        if (t < 64) {
            float xv = (t < MAXB) ? tgt[(size_t)b * (MAXB * 5) + t * 5 + 1] : 0.f;
            unsigned long long mk = __ballot(xv != 0.f);
            if (t == 0) {
                unsigned long long inv = (~mk) & ((1ull << MAXB) - 1ull);
                s_nv = inv ? (__ffsll(inv) - 1) : MAXB;
            }
        }
        if (t < MAXB) {
            const float* tp = tgt + (size_t)b * (MAXB * 5) + t * 5;
            s_cls[t] = tp[0];
            s_gx[t] = tp[1] * NW; s_gy[t] = tp[2] * NH;
            s_gw[t] = tp[3] * NW; s_gh[t] = tp[4] * NH;
        }
        __syncthreads();
        const int nv = s_nv;

        if (t < MAXB) {
            if (t < nv) {
                float gw = s_gw[t], gh = s_gh[t];
                float best = -1.f; int bn = 0;
                for (int a = 0; a < NA; ++a) {
                    float ca = fminf(c_aw[a], gw) * fminf(c_ah[a], gh);
                    float ua = c_aw[a] * c_ah[a] + gw * gh - ca;
                    float iou = ca / ua;
                    if (iou > best) { best = iou; bn = a; }   // first max wins
                }
                int gi = (int)s_gx[t], gj = (int)s_gy[t];
                s_bestn[t] = bn;
                s_flat[t] = (bn * NH + gj) * NW + gi;
            } else {
                s_flat[t] = -1 - t;
            }
        }
        __syncthreads();

        float loss = 0.f;
        if (t < nv) {
            // last-writer-wins dedupe (matches serial scatter order)
            bool winner = true;
            const int myf = s_flat[t];
            for (int t2 = t + 1; t2 < nv; ++t2) winner = winner && (s_flat[t2] != myf);
            if (winner) {
                const int a = s_bestn[t];
                const int gi = myf & (NW - 1);
                const int gj = (myf >> 6) & (NH - 1);
                const size_t base = (((size_t)b * NA + a) * 25) * HWSZ + gj * NW + gi;
                float x = sigmoidf_(out[base]);
                float y = sigmoidf_(out[base + HWSZ]);
                float w = __expf(out[base + 2 * HWSZ]);
                float h = __expf(out[base + 3 * HWSZ]);
                float conf = sigmoidf_(out[base + 4 * HWSZ]);

                float gx = s_gx[t], gy = s_gy[t], gw = s_gw[t], gh = s_gh[t];
                float tx = gx - (float)gi, ty = gy - (float)gj;
                float tw = gw / c_aw[a], th = gh / c_ah[a];
                float dx = x - tx, dy = y - ty, dw = w - tw, dh = h - th;
                loss += 0.5f * (dx * dx + dy * dy + dw * dw + dh * dh);

                float px = x + (float)gi, py = y + (float)gj;
                float pw = w * c_aw[a], ph = h * c_ah[a];
                float pxlo = px - 0.5f * pw, pxhi = px + 0.5f * pw;
                float pylo = py - 0.5f * ph, pyhi = py + 0.5f * ph;
                float parea = pw * ph;

                {   // assigned conf term minus what B added for this cell
                    float cw  = fminf(pxhi, gx + 0.5f * gw) - fmaxf(pxlo, gx - 0.5f * gw);
                    float chh = fminf(pyhi, gy + 0.5f * gh) - fmaxf(pylo, gy - 0.5f * gh);
                    float ca  = fmaxf(cw, 0.f) * fmaxf(chh, 0.f);
                    float ua  = parea + gw * gh - ca;
                    float tconf = ca / ua;
                    float mm = -1e30f;
                    for (int t2 = 0; t2 < nv; ++t2) {
                        float gw2 = s_gw[t2], gh2 = s_gh[t2];
                        float cw2 = fminf(pxhi, s_gx[t2] + 0.5f * gw2) -
                                    fmaxf(pxlo, s_gx[t2] - 0.5f * gw2);
                        float ch2 = fminf(pyhi, s_gy[t2] + 0.5f * gh2) -
                                    fmaxf(pylo, s_gy[t2] - 0.5f * gh2);
                        float ca2 = fmaxf(cw2, 0.f) * fmaxf(ch2, 0.f);
                        mm = fmaxf(mm, ca2 - 0.375f * gw2 * gh2);
                    }
                    bool sil = mm > 0.375f * parea;
                    float base_c = sil ? 0.f : 0.5f * conf * conf;
                    float dc = conf - tconf;
                    loss += 0.5f * dc * dc - base_c;
                }

                {   // class cross-entropy
                    const int lab = (int)s_cls[t];
                    float mmax = -1e30f, llab = 0.f;
                    for (int c = 0; c < NC; ++c) {
                        float l = out[base + (size_t)(5 + c) * HWSZ];
                        mmax = fmaxf(mmax, l);
                        if (c == lab) llab = l;
                    }
                    float se = 0.f;
                    for (int c = 0; c < NC; ++c)
                        se += __expf(out[base + (size_t)(5 + c) * HWSZ] - mmax);
                    loss += -(llab - mmax - logf(se));
                }
            }
        }
        if (t < 64) {
            for (int off = 32; off; off >>= 1) loss += __shfl_down(loss, off, 64);
            if (t == 0) partials[bid] = loss;
        }
        return;
    }

    // ---------------- B: default no-obj conf loss over a flat cell range ------
    const int g = bid - NABLK;          // 0..1023
    const int b = g >> 4;               // 16 blocks per batch (16*1280 = 5*4096)
    const int cell0 = g * CELLS_PER_BLK;

    // wave 0: validity ballot + masked box staging (single wave, no extra sync)
    if (t < 64) {
        float xv = (t < MAXB) ? tgt[(size_t)b * (MAXB * 5) + t * 5 + 1] : 0.f;
        unsigned long long mk = __ballot(xv != 0.f);
        unsigned long long inv = (~mk) & ((1ull << MAXB) - 1ull);
        int nv = inv ? (__ffsll(inv) - 1) : MAXB;
        if (t < MAXB) {
            bool val = t < nv;
            const float* tp = tgt + (size_t)b * (MAXB * 5) + t * 5;
            float gx = tp[1] * (float)NW, gy = tp[2] * (float)NH;
            float gw = tp[3] * (float)NW, gh = tp[4] * (float)NH;
            sbox[t][0] = val ? gx - 0.5f * gw : 0.f;
            sbox[t][1] = val ? gx + 0.5f * gw : 0.f;
            sbox[t][2] = val ? gy - 0.5f * gh : 0.f;
            sbox[t][3] = val ? gy + 0.5f * gh : 0.f;
            sbox[t][4] = val ? 0.375f * gw * gh : 1e30f;  // masked: never silences
            sbox[t][5] = gy;
            sbox[t][6] = val ? gh : -1e9f;                // invalid -> y-test false
        }
    }

    float pxlo[CELLS], pxhi[CELLS], pylo[CELLS], pyhi[CELLS];
    float m[CELLS], rhs[CELLS], hc[CELLS], fjh[CELLS];
    const float fi = (float)(t & 63);
#pragma unroll
    for (int cc = 0; cc < CELLS; ++cc) {
        const int cell = cell0 + cc * 256;     // block-uniform
        const int ba = cell >> 12;             // = b*5 + a (uniform per cc)
        const int a = ba - b * NA;
        const int hw = (cell & 4095) + t;
        const float fj = (float)(hw >> 6);     // wave-uniform row
        const float aw = c_aw[a], ah = c_ah[a];
        const float* p = out + (size_t)ba * (25 * HWSZ) + hw;
        float px = sigmoidf_(p[0]) + fi;
        float py = sigmoidf_(p[HWSZ]) + fj;
        float pw = __expf(p[2 * HWSZ]) * aw;
        float ph = __expf(p[3 * HWSZ]) * ah;
        float cf = sigmoidf_(p[4 * HWSZ]);
        pxlo[cc] = px - 0.5f * pw; pxhi[cc] = px + 0.5f * pw;
        pylo[cc] = py - 0.5f * ph; pyhi[cc] = py + 0.5f * ph;
        rhs[cc] = 0.375f * pw * ph;
        hc[cc]  = 0.5f * cf * cf;
        m[cc]   = -1e30f;
        fjh[cc] = fj + 0.5f;
    }
    __syncthreads();

    // ---- per-row conservative box masks (one ballot per cc; wave-uniform) ----
    // IoU>0.6 requires |j+0.5 - gy| < 0.7333*gh + 0.5 (necessary). Margin-widened.
    const int lane = t & 63;
    const int li = (lane < MAXB) ? lane : 0;
    const float ls_gy = sbox[li][5];
    const float ls_thr = fmaf(0.7334f, sbox[li][6], 0.51f);
    const bool lval = lane < MAXB;

    unsigned long long msk[CELLS];
    unsigned long long u = 0ull;
#pragma unroll
    for (int cc = 0; cc < CELLS; ++cc) {
        bool p = lval && (fabsf(fjh[cc] - ls_gy) < ls_thr);
        msk[cc] = __ballot(p);
        u |= msk[cc];
    }

    // ---- pruned box loop over union mask, 1-deep LDS prefetch ----
    if (u) {
        int bx = __ffsll(u) - 1;
        u &= u - 1;
        float4 bb = *reinterpret_cast<const float4*>(&sbox[bx][0]);
        float s2 = sbox[bx][4];
        for (;;) {
            const bool more = (u != 0ull);
            int nx = 0;
            float4 nb = bb; float ns = s2;
            if (more) {
                nx = __ffsll(u) - 1;
                u &= u - 1;
                nb = *reinterpret_cast<const float4*>(&sbox[nx][0]);
                ns = sbox[nx][4];
            }
#pragma unroll
            for (int cc = 0; cc < CELLS; ++cc) {
                if ((msk[cc] >> bx) & 1ull) {
                    float cw = fminf(pxhi[cc], bb.y) - fmaxf(pxlo[cc], bb.x);
                    float ch = fminf(pyhi[cc], bb.w) - fmaxf(pylo[cc], bb.z);
                    m[cc] = fmaxf(m[cc], fmaf(fmaxf(cw, 0.f), fmaxf(ch, 0.f), -s2));
                }
            }
            if (!more) break;
            bx = nx; bb = nb; s2 = ns;
        }
    }

    float v = 0.f;
#pragma unroll
    for (int cc = 0; cc < CELLS; ++cc) v += (m[cc] > rhs[cc]) ? 0.f : hc[cc];

    for (int off = 32; off; off >>= 1) v += __shfl_down(v, off, 64);
    if ((t & 63) == 0) sred[t >> 6] = v;
    __syncthreads();
    if (t == 0) partials[bid] = sred[0] + sred[1] + sred[2] + sred[3];
}

// ---------------- deterministic final reduce (2nd graph node) ----------------
__global__ __launch_bounds__(256) void reduce_kernel(const float* __restrict__ partials,
                                                     float* __restrict__ outp) {
    float v = 0.f;
    for (int idx = threadIdx.x; idx < NPART; idx += 256) v += partials[idx];
    for (int off = 32; off; off >>= 1) v += __shfl_down(v, off, 64);
    __shared__ float s[4];
    if ((threadIdx.x & 63) == 0) s[threadIdx.x >> 6] = v;
    __syncthreads();
    if (threadIdx.x == 0) outp[0] = s[0] + s[1] + s[2] + s[3];
}

extern "C" void kernel_launch(void* const* d_in, const int* in_sizes, int n_in,
                              void* d_out, int out_size, void* d_ws, size_t ws_size,
                              hipStream_t stream) {
    const float* out_t = (const float*)d_in[0];
    const float* tgt   = (const float*)d_in[1];
    float* loss = (float*)d_out;
    float* partials = (float*)d_ws;   // NPART floats, fully rewritten each call

    region_loss_main<<<NPART, 256, 0, stream>>>(out_t, tgt, partials);
    reduce_kernel<<<1, 256, 0, stream>>>(partials, loss);
}